// Round 12
// baseline (1137.857 us; speedup 1.0000x reference)
//
#include <hip/hip_runtime.h>

// MyRNN: B=128, T=80, E=100, V=10000, U=512
// 8 clusters x 32 members formed dynamically by physical XCD (s_getreg
// HW_REG_XCC_ID + one-time agent slot grab); ~157KB LDS -> 1 block/CU, grid
// 256 fills all CUs -> cluster == one XCD L2 BY CONSTRUCTION (R7-proven).
// Cluster c owns rows [16c,16c+16); member m owns cols [16m,16m+16) of
// rk0/rk1/k1 (stationary LDS, hi/lo bf16 split).
// Ladder: R1 3.9ms -> R4 921 -> R7 781 (data in XCD L2) -> R10 1026 (regr:
// grouped waits + extra barrier) -> R8/R11 HANGS: sc0/un-scoped SPIN polls
// don't observe remote stores (sc0 doesn't force L1 bypass; R7's sc0 data
// reads work only because 64KB/step self-evicts the 32KB L1 between epochs).
// RULE: polls = agent-scope atomic loads (MALL) ONLY; sc0 = bulk data reads
// after a MALL-certified sync, in the >=L1-footprint regime.
// R12 = R7 protocol skeleton + (a) round-B k1 gemm reads h0 hi/lo planes
// DIRECTLY from L2, all 32 loads in flight + one wait (no gather/barriers);
// (b) wave1-local MALL poll gates round B; wave0 runs ahead (emb prefetch,
// self-consumed dbuf); (c) round-A gather (packed h1 -> LDS) retained as the
// read-lifetime certificate that makes wave-autonomous posts race-free.

typedef __attribute__((ext_vector_type(8))) short short8;
typedef __attribute__((ext_vector_type(4))) float f32x4;

#define MFMA16(a,b,c) __builtin_amdgcn_mfma_f32_16x16x32_bf16(a,b,c,0,0,0)
#define LOAD_RLX(p)    __hip_atomic_load((p), __ATOMIC_RELAXED, __HIP_MEMORY_SCOPE_AGENT)
#define ADD_RLX(p,v)   __hip_atomic_fetch_add((p), (v), __ATOMIC_RELAXED, __HIP_MEMORY_SCOPE_AGENT)
#define L2LOADX4(dst, addr) \
  asm volatile("global_load_dwordx4 %0, %1, off sc0" : "=v"(dst) : "v"(addr))
#define WAIT_VM0() asm volatile("s_waitcnt vmcnt(0)" ::: "memory")

union U16x8 { uint4 u; short8 s; };

__device__ __forceinline__ short f2bf(float v){
  unsigned u = __float_as_uint(v);
  u = (u + 0x7fffu + ((u >> 16) & 1u)) >> 16;   // RNE to bf16
  return (short)u;
}
__device__ __forceinline__ float bf2f(short s){
  return __uint_as_float(((unsigned)(unsigned short)s) << 16);
}
__device__ __forceinline__ float fast_tanh(float x){
  x = fminf(15.f, fmaxf(-15.f, x));
  float e = __expf(2.f * x);
  return (e - 1.f) * __builtin_amdgcn_rcpf(e + 1.f);
}

__launch_bounds__(128, 1)
__global__ void rnn_kernel(const int* __restrict__ tokens,
                           const float* __restrict__ emb,
                           const float* __restrict__ k0,
                           const float* __restrict__ rk0,
                           const float* __restrict__ b0,
                           const float* __restrict__ k1,
                           const float* __restrict__ rk1,
                           const float* __restrict__ b1,
                           const float* __restrict__ wd,
                           const float* __restrict__ bd,
                           float* __restrict__ out,
                           char* __restrict__ ws)
{
  constexpr int T = 80, E = 100, U = 512;
  const int tid  = threadIdx.x;
  const int w    = tid >> 6;          // wave id (0/1)
  const int lane = tid & 63;
  const int m    = lane & 15;         // row (A) / col (B,C)
  const int q    = lane >> 4;         // quad 0..3

  __shared__ __align__(16) short sW[6][16][520];    // rk0 hi/lo, rk1 hi/lo, k1 hi/lo : [col][k]
  __shared__ __align__(16) short sH[2][16][520];    // gathered h1 hi,lo : [row][k]
  __shared__ __align__(16) short sE[2][2][16][128]; // emb dbuf [buf][hi/lo][row][e] (K pad 128)
  __shared__ __align__(16) short sK0[2][16][128];   // k0 slice hi,lo : [col][k]
  __shared__ unsigned short sTok[16][80];
  __shared__ float sB0[16], sB1[16];
  __shared__ float sRed[16][8];
  __shared__ int   sReg[2];

  int*      cnts   = (int*)ws;                   // 8 counters, 64B stride (MALL)
  int*      regCnt = (int*)(ws + 512);           // 8 registration counters (MALL, one-time)
  unsigned* hPk    = (unsigned*)(ws + 16*1024);  // h1 packed (hi<<16|lo) [128][512]
  short*    h0Hi   = (short*)(hPk + 128*U);      // h0 hi plane [128][512]
  short*    h0Lo   = h0Hi + 128*U;               // h0 lo plane

  // -------- dynamic cluster formation: cluster id = physical XCD --------
  int xcc;
  asm volatile("s_getreg_b32 %0, hwreg(HW_REG_XCC_ID)" : "=s"(xcc));
  if (tid == 0){
    int slot = ADD_RLX(regCnt + (xcc & 7)*16, 1);   // 0..31 within this XCD
    sReg[0] = xcc & 7;
    sReg[1] = slot;
  }
  __syncthreads();
  const int cl  = sReg[0];
  const int mem = sReg[1];
  int* cnt = cnts + cl*16;

  // ---------------- prologue: stationary weights -> LDS ----------------
  const float* mats[3] = { rk0, rk1, k1 };
  for (int mi = 0; mi < 3; ++mi){
    const float* G = mats[mi];
    for (int i = tid; i < 16*U; i += 128){
      int k = i >> 4, c = i & 15;
      float v  = G[k*U + mem*16 + c];
      short hi = f2bf(v);
      short lo = f2bf(v - bf2f(hi));
      sW[2*mi+0][c][k] = hi;
      sW[2*mi+1][c][k] = lo;
    }
  }
  for (int i = tid; i < 2*2*16*128; i += 128) ((short*)sE)[i] = 0;
  for (int i = tid; i < 2*16*128;   i += 128) ((short*)sK0)[i] = 0;
  __syncthreads();
  for (int i = tid; i < 16*E; i += 128){
    int e = i >> 4, c = i & 15;
    float v  = k0[e*U + mem*16 + c];
    short hi = f2bf(v);
    short lo = f2bf(v - bf2f(hi));
    sK0[0][c][e] = hi; sK0[1][c][e] = lo;
  }
  for (int i = tid; i < 16*T; i += 128){
    int r = i / T, t = i - r*T;
    sTok[r][t] = (unsigned short)tokens[(cl*16 + r)*T + t];
  }
  if (tid < 16){ sB0[tid] = b0[mem*16 + tid]; sB1[tid] = b1[mem*16 + tid]; }
  __syncthreads();
  // stage emb(0) into sE buf0
  for (int i = tid; i < 16*E; i += 128){
    int r = i / E, e = i - r*E;
    float v  = emb[(int)sTok[r][0]*E + e];
    short hi = f2bf(v);
    short lo = f2bf(v - bf2f(hi));
    sE[0][0][r][e] = hi; sE[0][1][r][e] = lo;
  }
  __syncthreads();

  // polls: MALL atomic loads ONLY (R8/R11 lesson)
  auto poll_t0 = [&](int target){
    if (tid == 0){ while (LOAD_RLX(cnt) < target) {} }
  };
  auto wvpoll = [&](int target){                 // wave-local (round B, wave1)
    if (lane == 0){ while (LOAD_RLX(cnt) < target) {} }
    asm volatile("" ::: "memory");
  };
  auto post = [&](){
    WAIT_VM0();                                  // own stores drained to L2
    if (lane == 0) ADD_RLX(cnt, 1);
  };
  // round-A gather: packed h1 slice (32KB) -> sH hi/lo; 16 loads, one wait
  auto gatherH = [&](){
    const uint4* s = (const uint4*)(hPk + cl*16*U);   // 2048 uint4
    uint4 r[16];
    #pragma unroll
    for (int j = 0; j < 16; ++j) L2LOADX4(r[j], &s[j*128 + tid]);
    WAIT_VM0();
    #pragma unroll
    for (int j = 0; j < 16; ++j){
      int i = j*128 + tid, row = i >> 7, c = (i & 127) * 4;
      uint2 hh, ll;
      hh.x = (r[j].x >> 16)     | (r[j].y & 0xffff0000u);
      hh.y = (r[j].z >> 16)     | (r[j].w & 0xffff0000u);
      ll.x = (r[j].x & 0xffffu) | (r[j].y << 16);
      ll.y = (r[j].z & 0xffffu) | (r[j].w << 16);
      *(uint2*)&sH[0][row][c] = hh;
      *(uint2*)&sH[1][row][c] = ll;
    }
  };

  const f32x4 zero4 = {0.f, 0.f, 0.f, 0.f};

  // ---------------- recurrence ----------------
  // counter: +32 after round A (wave0s), +32 after round B (wave1s).
  for (int t = 0; t < T; ++t){
    if (t > 0) poll_t0(64*t);            // all h1(t-1) posted
    __syncthreads();
    if (t > 0) gatherH();                // hPk reads retired before barrier
    __syncthreads();                     // gather visible; certifies reads for posts

    if (w == 0){
      // ---- round A: h0 = tanh(x@k0 + h@rk0 + b0)
      f32x4 za = zero4, zb = zero4, zc = zero4, zd = zero4;
      const int eb = t & 1;
      #pragma unroll
      for (int kk = 0; kk < 4; ++kk){    // x@k0 (LDS)
        short8 ah = *(const short8*)&sE[eb][0][m][kk*32 + q*8];
        short8 al = *(const short8*)&sE[eb][1][m][kk*32 + q*8];
        short8 bh = *(const short8*)&sK0[0][m][kk*32 + q*8];
        short8 bl = *(const short8*)&sK0[1][m][kk*32 + q*8];
        za = MFMA16(ah, bh, za); zb = MFMA16(al, bh, zb);
        zc = MFMA16(ah, bl, zc); zd = MFMA16(al, bl, zd);
      }
      if (t > 0){
        #pragma unroll
        for (int kk = 0; kk < 16; ++kk){ // h@rk0 (LDS)
          short8 ah = *(const short8*)&sH[0][m][kk*32 + q*8];
          short8 al = *(const short8*)&sH[1][m][kk*32 + q*8];
          short8 bh = *(const short8*)&sW[0][m][kk*32 + q*8];
          short8 bl = *(const short8*)&sW[1][m][kk*32 + q*8];
          za = MFMA16(ah, bh, za); zb = MFMA16(al, bh, zb);
          zc = MFMA16(ah, bl, zc); zd = MFMA16(al, bl, zd);
        }
      }
      f32x4 z = za; z += zb; z += zc; z += zd;
      #pragma unroll
      for (int r = 0; r < 4; ++r){       // h0 -> XCD L2 planes
        float h0v = fast_tanh(z[r] + sB0[m]);
        short hi = f2bf(h0v);
        short lo = f2bf(h0v - bf2f(hi));
        int idx = (cl*16 + q*4 + r)*U + mem*16 + m;
        h0Hi[idx] = hi; h0Lo[idx] = lo;
      }
      post();                            // counter -> 64t+32 when all wave0s in
      if (t + 1 < T){                    // emb prefetch (self-consumed dbuf)
        const int nb = (t + 1) & 1;
        for (int i = lane; i < 16*E; i += 64){
          int r = i / E, e = i - r*E;
          float v  = emb[(int)sTok[r][t+1]*E + e];
          short hi = f2bf(v);
          short lo = f2bf(v - bf2f(hi));
          sE[nb][0][r][e] = hi; sE[nb][1][r][e] = lo;
        }
      }
    } else {
      // ---- round B prep: h@rk1 partial from sH (LDS)
      f32x4 z1a = zero4, z1b = zero4, z1c = zero4, z1d = zero4;
      if (t > 0){
        #pragma unroll
        for (int kk = 0; kk < 16; ++kk){
          short8 ah = *(const short8*)&sH[0][m][kk*32 + q*8];
          short8 al = *(const short8*)&sH[1][m][kk*32 + q*8];
          short8 bh = *(const short8*)&sW[2][m][kk*32 + q*8];
          short8 bl = *(const short8*)&sW[3][m][kk*32 + q*8];
          z1a = MFMA16(ah, bh, z1a); z1b = MFMA16(al, bh, z1b);
          z1c = MFMA16(ah, bl, z1c); z1d = MFMA16(al, bl, z1d);
        }
      }
      // ---- round B: h1 = tanh(h0@k1 + h@rk1 + b1); h0 direct from L2
      wvpoll(64*t + 32);                 // all h0(t) posted (MALL)
      {
        const short* ph = h0Hi + (cl*16 + m)*U + q*8;
        const short* pl = h0Lo + (cl*16 + m)*U + q*8;
        U16x8 rh[16], rl[16];
        #pragma unroll
        for (int kk = 0; kk < 16; ++kk){ // ALL 32 loads in flight, ONE wait
          L2LOADX4(rh[kk].u, ph + kk*32);
          L2LOADX4(rl[kk].u, pl + kk*32);
        }
        WAIT_VM0();
        f32x4 za = zero4, zb = zero4, zc = zero4, zd = zero4;
        #pragma unroll
        for (int kk = 0; kk < 16; ++kk){
          short8 bh = *(const short8*)&sW[4][m][kk*32 + q*8];
          short8 bl = *(const short8*)&sW[5][m][kk*32 + q*8];
          za = MFMA16(rh[kk].s, bh, za); zb = MFMA16(rl[kk].s, bh, zb);
          zc = MFMA16(rh[kk].s, bl, zc); zd = MFMA16(rl[kk].s, bl, zd);
        }
        f32x4 z = za; z += zb; z += zc; z += zd;
        z += z1a; z += z1b; z += z1c; z += z1d;
        #pragma unroll
        for (int r = 0; r < 4; ++r){     // h1 -> XCD L2 (packed)
          float h1v = fast_tanh(z[r] + sB1[m]);
          short hi = f2bf(h1v);
          short lo = f2bf(h1v - bf2f(hi));
          unsigned pk = ((unsigned)(unsigned short)hi << 16) | (unsigned short)lo;
          hPk[(cl*16 + q*4 + r)*U + mem*16 + m] = pk;
        }
      }
      post();                            // counter -> 64(t+1) when all wave1s in
    }
    // barrier sequence per wave per step: B1 (loop top), B2 (post-gather) — aligned
  }

  // ---------------- epilogue: logits = h@wd + bd ; sigmoid ----------------
  if (mem == 0){
    poll_t0(64*T);
    __syncthreads();
    {
      int row = tid >> 3, seg = tid & 7;
      const uint4* s = (const uint4*)(hPk + (cl*16 + row)*U + seg*64);
      uint4 r[16];
      #pragma unroll
      for (int j = 0; j < 16; ++j) L2LOADX4(r[j], &s[j]);
      WAIT_VM0();
      float acc = 0.f;
      #pragma unroll
      for (int j = 0; j < 16; ++j){
        #pragma unroll
        for (int e = 0; e < 4; ++e){
          unsigned p = ((const unsigned*)&r[j])[e];
          float hv = bf2f((short)(p >> 16)) + bf2f((short)(p & 0xffffu));
          acc += hv * wd[seg*64 + j*4 + e];
        }
      }
      sRed[row][seg] = acc;
    }
    __syncthreads();
    if (tid < 16){
      float s = bd[0];
      #pragma unroll
      for (int j = 0; j < 8; ++j) s += sRed[tid][j];
      out[cl*16 + tid] = 1.f / (1.f + __expf(-s));
    }
  }

  // replay hygiene (R7-proven): write back dirty L2 exchange lines
  __threadfence();
}

extern "C" void kernel_launch(void* const* d_in, const int* in_sizes, int n_in,
                              void* d_out, int out_size, void* d_ws, size_t ws_size,
                              hipStream_t stream) {
  const int*   tokens = (const int*)  d_in[0];
  const float* emb    = (const float*)d_in[1];
  const float* k0     = (const float*)d_in[2];
  const float* rk0    = (const float*)d_in[3];
  const float* b0     = (const float*)d_in[4];
  const float* k1     = (const float*)d_in[5];
  const float* rk1    = (const float*)d_in[6];
  const float* b1     = (const float*)d_in[7];
  const float* wd     = (const float*)d_in[8];
  const float* bd     = (const float*)d_in[9];

  // Zero sync + registration counters (0xAA poison breaks monotonic arith).
  hipMemsetAsync(d_ws, 0, 4096, stream);

  hipLaunchKernelGGL(rnn_kernel, dim3(256), dim3(128), 0, stream,
                     tokens, emb, k0, rk0, b0, k1, rk1, b1, wd, bd,
                     (float*)d_out, (char*)d_ws);
}